// Round 2
// baseline (1803.289 us; speedup 1.0000x reference)
//
#include <hip/hip_runtime.h>
#include <hip/hip_bf16.h>

#define HEADS 8
#define BB 32
#define CC 512
#define LL 32
#define NN 1024   // LL*LL tokens
#define DD 64     // CC/HEADS

typedef __hip_bfloat16 bf16;

__device__ __forceinline__ float bf2f(unsigned int u16) {
    return __uint_as_float(u16 << 16);
}

// Generic 4-element (consecutive) load -> float4
__device__ __forceinline__ float4 ld4(const float* p) {
    return *(const float4*)p;
}
__device__ __forceinline__ float4 ld4(const bf16* p) {
    uint2 u = *(const uint2*)p;
    float4 f;
    f.x = bf2f(u.x & 0xffffu);
    f.y = bf2f(u.x >> 16);
    f.z = bf2f(u.y & 0xffffu);
    f.w = bf2f(u.y >> 16);
    return f;
}
// Generic scalar store
__device__ __forceinline__ void st1(float* p, float v) { *p = v; }
__device__ __forceinline__ void st1(bf16* p, float v)  { *p = __float2bfloat16(v); }

// ---------------------------------------------------------------------------
// Kernel A: QKV 1x1-conv GEMM.  qkv[b][o][m] = sum_c W[o][c] * x[b][c][m]
// Epilogue writes Q/K'/V in head-major layout [B][p][n][d];
// K' = K + rp  (rp[c at pixel m] = h_pos[h][c] + w_pos[w][c], m = h*32+w)
// TQK = storage type for Q,K'; TV = storage type for V.
// Block: 64 (o) x 64 (m) tile, 256 threads, 4x4 micro-tile per thread.
// ---------------------------------------------------------------------------
template<typename TQK, typename TV>
__global__ __launch_bounds__(256) void qkv_kernel(
    const float* __restrict__ x,      // [B][C][N]
    const float* __restrict__ W,      // [3C][C]
    const float* __restrict__ h_pos,  // [L][C]
    const float* __restrict__ w_pos,  // [L][C]
    TQK* __restrict__ Qg, TQK* __restrict__ Kg, TV* __restrict__ Vg)
{
    __shared__ float Wt[16][68];  // [kk][oo]  (W tile transposed)
    __shared__ float Xt[16][68];  // [kk][mm]

    const int tid = threadIdx.x;
    const int tx = tid & 15, ty = tid >> 4;
    const int o0 = blockIdx.x * 64;            // output-channel tile (0..1472)
    const int by = blockIdx.y;
    const int b  = by >> 4;                    // batch
    const int m0 = (by & 15) << 6;             // pixel tile within batch

    float acc[4][4];
    #pragma unroll
    for (int i = 0; i < 4; ++i)
        #pragma unroll
        for (int j = 0; j < 4; ++j) acc[i][j] = 0.f;

    const int w_oo = tid >> 2, w_kq = (tid & 3) << 2;
    const int x_kk = tid >> 4, x_mq = (tid & 15) << 2;
    const float* Wrow = W + (size_t)(o0 + w_oo) * CC + w_kq;
    const float* Xrow = x + ((size_t)b * CC + x_kk) * NN + m0 + x_mq;

    for (int ct = 0; ct < 32; ++ct) {
        const int c0 = ct << 4;
        float4 wv = *(const float4*)(Wrow + c0);
        float4 xv = *(const float4*)(Xrow + (size_t)c0 * NN);
        Wt[w_kq + 0][w_oo] = wv.x;
        Wt[w_kq + 1][w_oo] = wv.y;
        Wt[w_kq + 2][w_oo] = wv.z;
        Wt[w_kq + 3][w_oo] = wv.w;
        *(float4*)&Xt[x_kk][x_mq] = xv;
        __syncthreads();
        #pragma unroll
        for (int kk = 0; kk < 16; ++kk) {
            float4 a4 = *(const float4*)&Wt[kk][ty << 2];
            float4 b4 = *(const float4*)&Xt[kk][tx << 2];
            float av[4] = {a4.x, a4.y, a4.z, a4.w};
            float bv[4] = {b4.x, b4.y, b4.z, b4.w};
            #pragma unroll
            for (int i = 0; i < 4; ++i)
                #pragma unroll
                for (int j = 0; j < 4; ++j)
                    acc[i][j] = fmaf(av[i], bv[j], acc[i][j]);
        }
        __syncthreads();
    }

    // Epilogue: o0 is 64-aligned, 512%64==0 -> whole tile is one region/head.
    const int region = o0 >> 9;          // 0=Q, 1=K, 2=V
    const int p = (o0 >> 6) & 7;         // head
    const size_t base = (size_t)(b * HEADS + p) * NN * DD;
    if (region < 2) {
        TQK* dst = (region == 0) ? Qg : Kg;
        #pragma unroll
        for (int i = 0; i < 4; ++i) {
            const int dd = (ty << 2) + i;
            #pragma unroll
            for (int j = 0; j < 4; ++j) {
                const int m = m0 + (tx << 2) + j;
                float v = acc[i][j];
                if (region == 1) {
                    const int c = p * DD + dd;
                    v += h_pos[(m >> 5) * CC + c] + w_pos[(m & 31) * CC + c];
                }
                st1(dst + base + (size_t)m * DD + dd, v);
            }
        }
    } else {
        #pragma unroll
        for (int i = 0; i < 4; ++i) {
            const int dd = (ty << 2) + i;
            #pragma unroll
            for (int j = 0; j < 4; ++j) {
                const int m = m0 + (tx << 2) + j;
                st1(Vg + base + (size_t)m * DD + dd, acc[i][j]);
            }
        }
    }
}

// ---------------------------------------------------------------------------
// Kernel B: flash attention (no score materialization).
// Block = (b, head, 64-row Q tile); 256 threads; online softmax.
// Qs/Ks staged transposed [d][m] in LDS for float4 micro-kernel reads.
// P overlays Ks (Ks fully consumed before P is written) -> LDS ~57 KB.
// ---------------------------------------------------------------------------
template<typename TQK, typename TV>
__global__ __launch_bounds__(256) void attn_kernel(
    const TQK* __restrict__ Qg, const TQK* __restrict__ Kg,
    const TV* __restrict__ Vg, float* __restrict__ out)
{
    __shared__ float Qs[64][68];   // [dd][m]
    __shared__ float Ks[64][68];   // [dd][nn]  -- reused as Ps[r][c] after S
    __shared__ float Vs[64][68];   // [kk][dd]
    __shared__ float red[64][16];
    __shared__ float mrow[64], lrow[64], arow[64];

    const int tid = threadIdx.x;
    const int tx = tid & 15, ty = tid >> 4;
    const int r0 = ty << 2, c0 = tx << 2;
    const int qt = blockIdx.x;   // q tile 0..15
    const int p  = blockIdx.y;   // head
    const int b  = blockIdx.z;   // batch

    const size_t head_base = (size_t)(b * HEADS + p) * NN * DD;
    const TQK* Qp = Qg + head_base + (size_t)qt * 64 * DD;
    const TQK* Kp = Kg + head_base;
    const TV*  Vp = Vg + head_base;

    // Stage Q transposed (once)
    {
        const int d4 = tx << 2;
        #pragma unroll
        for (int it = 0; it < 4; ++it) {
            const int m = it * 16 + ty;
            float4 qv = ld4(Qp + (size_t)m * DD + d4);
            Qs[d4 + 0][m] = qv.x;
            Qs[d4 + 1][m] = qv.y;
            Qs[d4 + 2][m] = qv.z;
            Qs[d4 + 3][m] = qv.w;
        }
    }
    if (tid < 64) { mrow[tid] = -__builtin_inff(); lrow[tid] = 0.f; }

    float o_acc[4][4];
    #pragma unroll
    for (int i = 0; i < 4; ++i)
        #pragma unroll
        for (int j = 0; j < 4; ++j) o_acc[i][j] = 0.f;

    for (int kt = 0; kt < 16; ++kt) {
        __syncthreads();  // covers Q-stage/init (kt=0) and prior PV reads of Ks/Vs
        // Stage K tile transposed + V tile straight
        {
            const int d4 = tx << 2;
            #pragma unroll
            for (int it = 0; it < 4; ++it) {
                const int nl = it * 16 + ty;
                float4 kv = ld4(Kp + (size_t)(kt * 64 + nl) * DD + d4);
                Ks[d4 + 0][nl] = kv.x;
                Ks[d4 + 1][nl] = kv.y;
                Ks[d4 + 2][nl] = kv.z;
                Ks[d4 + 3][nl] = kv.w;
                float4 vf = ld4(Vp + (size_t)(kt * 64 + nl) * DD + d4);
                *(float4*)&Vs[nl][d4] = vf;
            }
        }
        __syncthreads();

        // S tile = Q K'^T  (4x4 per thread)
        float s[4][4];
        #pragma unroll
        for (int i = 0; i < 4; ++i)
            #pragma unroll
            for (int j = 0; j < 4; ++j) s[i][j] = 0.f;
        for (int dd = 0; dd < 64; ++dd) {
            float4 q4 = *(const float4*)&Qs[dd][r0];
            float4 k4 = *(const float4*)&Ks[dd][c0];
            float qa[4] = {q4.x, q4.y, q4.z, q4.w};
            float ka[4] = {k4.x, k4.y, k4.z, k4.w};
            #pragma unroll
            for (int i = 0; i < 4; ++i)
                #pragma unroll
                for (int j = 0; j < 4; ++j)
                    s[i][j] = fmaf(qa[i], ka[j], s[i][j]);
        }

        // Row-max partials
        #pragma unroll
        for (int i = 0; i < 4; ++i) {
            float lm = fmaxf(fmaxf(s[i][0], s[i][1]), fmaxf(s[i][2], s[i][3]));
            red[r0 + i][tx] = lm;
        }
        __syncthreads();
        if (tid < 64) {
            float t = red[tid][0];
            #pragma unroll
            for (int j = 1; j < 16; ++j) t = fmaxf(t, red[tid][j]);
            const float mo = mrow[tid];
            const float mn = fmaxf(mo, t);
            arow[tid] = __expf(mo - mn);   // 0 on first tile (mo = -inf)
            mrow[tid] = mn;
        }
        __syncthreads();

        // P = exp(S - m); write P into Ks buffer (Ks consumed); rescale O
        #pragma unroll
        for (int i = 0; i < 4; ++i) {
            const float mn = mrow[r0 + i];
            const float a  = arow[r0 + i];
            float ls = 0.f;
            #pragma unroll
            for (int j = 0; j < 4; ++j) {
                float pe = __expf(s[i][j] - mn);
                Ks[r0 + i][c0 + j] = pe;   // Ps alias
                ls += pe;
            }
            red[r0 + i][tx] = ls;
            #pragma unroll
            for (int j = 0; j < 4; ++j) o_acc[i][j] *= a;
        }
        __syncthreads();
        if (tid < 64) {
            float t = 0.f;
            #pragma unroll
            for (int j = 0; j < 16; ++j) t += red[tid][j];
            lrow[tid] = arow[tid] * lrow[tid] + t;
        }

        // O += P V   (P rows from Ks alias, V cols float4)
        for (int kk = 0; kk < 64; ++kk) {
            float4 v4 = *(const float4*)&Vs[kk][c0];
            float va[4] = {v4.x, v4.y, v4.z, v4.w};
            #pragma unroll
            for (int i = 0; i < 4; ++i) {
                float pv = Ks[r0 + i][kk];   // Ps alias
                #pragma unroll
                for (int j = 0; j < 4; ++j)
                    o_acc[i][j] = fmaf(pv, va[j], o_acc[i][j]);
            }
        }
    }
    __syncthreads();  // final lrow visible

    // Epilogue: out[b][p*64+dd][m] = O[m][dd] / l[m]
    #pragma unroll
    for (int i = 0; i < 4; ++i) {
        const int m = qt * 64 + r0 + i;
        const float inv = 1.0f / lrow[r0 + i];
        #pragma unroll
        for (int j = 0; j < 4; ++j) {
            const int dd = c0 + j;
            out[((size_t)(b * CC + p * DD + dd)) * NN + m] = o_acc[i][j] * inv;
        }
    }
}

extern "C" void kernel_launch(void* const* d_in, const int* in_sizes, int n_in,
                              void* d_out, int out_size, void* d_ws, size_t ws_size,
                              hipStream_t stream) {
    const float* x     = (const float*)d_in[0];
    const float* qkv_w = (const float*)d_in[1];
    const float* h_pos = (const float*)d_in[2];
    const float* w_pos = (const float*)d_in[3];
    float* out = (float*)d_out;

    const size_t PT = (size_t)BB * HEADS * NN * DD;  // 16,777,216 elems per tensor
    const size_t need_f32   = 3 * PT * sizeof(float);                    // ~201 MB
    const size_t need_mixed = 2 * PT * sizeof(float) + PT * sizeof(bf16); // ~168 MB

    const dim3 gA(24, 512), bA(256);
    const dim3 gB(16, HEADS, BB), bB(256);

    if (ws_size >= need_f32) {
        // Full fp32 intermediates: score + V exact (absmax ~1e-4)
        float* Qg = (float*)d_ws;
        float* Kg = Qg + PT;
        float* Vg = Kg + PT;
        qkv_kernel<float, float><<<gA, bA, 0, stream>>>(x, qkv_w, h_pos, w_pos, Qg, Kg, Vg);
        attn_kernel<float, float><<<gB, bB, 0, stream>>>(Qg, Kg, Vg, out);
    } else if (ws_size >= need_mixed) {
        // fp32 Q,K (exact scores); bf16 V (error ~1e-2, under 1.06e-1 threshold)
        float* Qg = (float*)d_ws;
        float* Kg = Qg + PT;
        bf16*  Vg = (bf16*)(Kg + PT);
        qkv_kernel<float, bf16><<<gA, bA, 0, stream>>>(x, qkv_w, h_pos, w_pos, Qg, Kg, Vg);
        attn_kernel<float, bf16><<<gB, bB, 0, stream>>>(Qg, Kg, Vg, out);
    } else {
        // Last-resort bf16 everything (known marginal precision)
        bf16* Qg = (bf16*)d_ws;
        bf16* Kg = Qg + PT;
        bf16* Vg = Kg + PT;
        qkv_kernel<bf16, bf16><<<gA, bA, 0, stream>>>(x, qkv_w, h_pos, w_pos, Qg, Kg, Vg);
        attn_kernel<bf16, bf16><<<gB, bB, 0, stream>>>(Qg, Kg, Vg, out);
    }
}

// Round 4
// 1072.083 us; speedup vs baseline: 1.6820x; 1.6820x over previous
//
#include <hip/hip_runtime.h>
#include <hip/hip_bf16.h>

#define HEADS 8
#define BB 32
#define CC 512
#define LL 32
#define NN 1024   // tokens
#define DD 64     // head dim

typedef __bf16 bf16_t;
typedef __attribute__((ext_vector_type(8))) __bf16 bf16x8;
typedef __attribute__((ext_vector_type(4))) float f32x4;

// ---------------------------------------------------------------------------
// Kernel A: QKV 1x1-conv GEMM (fp32 VALU).  qkv[b][o][m] = sum_c W[o][c] x[b][c][m]
// Epilogue:
//   Q -> Qhi/Qlo bf16 split, layout [B][p][n][d]
//   K -> K' = K + rp, then Khi/Klo bf16 split, layout [B][p][n][d]
//   V -> Vt bf16, TRANSPOSED layout [B][p][d][n]
// ---------------------------------------------------------------------------
__global__ __launch_bounds__(256) void qkv_kernel(
    const float* __restrict__ x,      // [B][C][N]
    const float* __restrict__ W,      // [3C][C]
    const float* __restrict__ h_pos,  // [L][C]
    const float* __restrict__ w_pos,  // [L][C]
    bf16_t* __restrict__ Qhi, bf16_t* __restrict__ Qlo,
    bf16_t* __restrict__ Khi, bf16_t* __restrict__ Klo,
    bf16_t* __restrict__ Vt)
{
    __shared__ float Wt[16][68];  // [kk][oo]
    __shared__ float Xt[16][68];  // [kk][mm]

    const int tid = threadIdx.x;
    const int tx = tid & 15, ty = tid >> 4;
    const int o0 = blockIdx.x * 64;
    const int by = blockIdx.y;
    const int b  = by >> 4;
    const int m0 = (by & 15) << 6;

    float acc[4][4];
    #pragma unroll
    for (int i = 0; i < 4; ++i)
        #pragma unroll
        for (int j = 0; j < 4; ++j) acc[i][j] = 0.f;

    const int w_oo = tid >> 2, w_kq = (tid & 3) << 2;
    const int x_kk = tid >> 4, x_mq = (tid & 15) << 2;
    const float* Wrow = W + (size_t)(o0 + w_oo) * CC + w_kq;
    const float* Xrow = x + ((size_t)b * CC + x_kk) * NN + m0 + x_mq;

    for (int ct = 0; ct < 32; ++ct) {
        const int c0 = ct << 4;
        float4 wv = *(const float4*)(Wrow + c0);
        float4 xv = *(const float4*)(Xrow + (size_t)c0 * NN);
        Wt[w_kq + 0][w_oo] = wv.x;
        Wt[w_kq + 1][w_oo] = wv.y;
        Wt[w_kq + 2][w_oo] = wv.z;
        Wt[w_kq + 3][w_oo] = wv.w;
        *(float4*)&Xt[x_kk][x_mq] = xv;
        __syncthreads();
        #pragma unroll
        for (int kk = 0; kk < 16; ++kk) {
            float4 a4 = *(const float4*)&Wt[kk][ty << 2];
            float4 b4 = *(const float4*)&Xt[kk][tx << 2];
            float av[4] = {a4.x, a4.y, a4.z, a4.w};
            float bv[4] = {b4.x, b4.y, b4.z, b4.w};
            #pragma unroll
            for (int i = 0; i < 4; ++i)
                #pragma unroll
                for (int j = 0; j < 4; ++j)
                    acc[i][j] = fmaf(av[i], bv[j], acc[i][j]);
        }
        __syncthreads();
    }

    const int region = o0 >> 9;          // 0=Q, 1=K, 2=V
    const int p = (o0 >> 6) & 7;         // head
    const size_t base = (size_t)(b * HEADS + p) * NN * DD;
    if (region < 2) {
        bf16_t* dhi = (region == 0) ? Qhi : Khi;
        bf16_t* dlo = (region == 0) ? Qlo : Klo;
        #pragma unroll
        for (int i = 0; i < 4; ++i) {
            const int dd = (ty << 2) + i;
            #pragma unroll
            for (int j = 0; j < 4; ++j) {
                const int m = m0 + (tx << 2) + j;
                float v = acc[i][j];
                if (region == 1) {
                    const int c = p * DD + dd;
                    v += h_pos[(m >> 5) * CC + c] + w_pos[(m & 31) * CC + c];
                }
                bf16_t h = (bf16_t)v;
                bf16_t l = (bf16_t)(v - (float)h);
                dhi[base + (size_t)m * DD + dd] = h;
                dlo[base + (size_t)m * DD + dd] = l;
            }
        }
    } else {
        #pragma unroll
        for (int i = 0; i < 4; ++i) {
            const int dd = (ty << 2) + i;
            #pragma unroll
            for (int j = 0; j < 4; ++j) {
                const int m = m0 + (tx << 2) + j;
                Vt[base + (size_t)dd * NN + m] = (bf16_t)acc[i][j];
            }
        }
    }
}

// ---------------------------------------------------------------------------
// Kernel B: MFMA flash attention.
// Block = (qt, head, batch): 64 q-rows, 4 waves (16 q-rows each).
// S via 3-term bf16 hi/lo split (fp32-accurate); online softmax in registers;
// P -> per-wave LDS (C-layout -> A-layout transform); PV via MFMA.
// RACE FIX (R4): __syncthreads() between P ds_write and PV ds_read_b128 —
// same-wave LDS write->read without a fence was bypassed under warm-cache
// timing (first launch passed, graph replays diverged).
// MFMA 16x16x32_bf16 layouts:
//   A[m=lane&15][k=quad*8+j]  (contiguous 8 bf16 in k)
//   B[k=quad*8+j][n=lane&15]
//   C/D: row(m)=quad*4+reg, col(n)=lane&15
// ---------------------------------------------------------------------------
#define KST 72   // LDS row stride (bf16 elems)

__global__ __launch_bounds__(256) void attn_kernel(
    const bf16_t* __restrict__ Qhi, const bf16_t* __restrict__ Qlo,
    const bf16_t* __restrict__ Khi, const bf16_t* __restrict__ Klo,
    const bf16_t* __restrict__ Vt,  float* __restrict__ out)
{
    __shared__ bf16_t KhiS[64 * KST];
    __shared__ bf16_t KloS[64 * KST];
    __shared__ bf16_t VtS [64 * KST];
    __shared__ bf16_t PS  [4][16 * KST];

    const int tid  = threadIdx.x;
    const int wave = tid >> 6;
    const int lane = tid & 63;
    const int ln   = lane & 15;
    const int quad = lane >> 4;

    const int qt = blockIdx.x;
    const int p  = blockIdx.y;
    const int b  = blockIdx.z;
    const size_t hb = (size_t)(b * HEADS + p) * NN * DD;

    // Q fragments (A-layout) straight from global, once.
    const int qrow = qt * 64 + wave * 16 + ln;
    bf16x8 qh[2], ql[2];
    #pragma unroll
    for (int ks = 0; ks < 2; ++ks) {
        const size_t off = hb + (size_t)qrow * DD + ks * 32 + quad * 8;
        qh[ks] = *(const bf16x8*)(Qhi + off);
        ql[ks] = *(const bf16x8*)(Qlo + off);
    }

    f32x4 o[4];
    #pragma unroll
    for (int dt = 0; dt < 4; ++dt) o[dt] = (f32x4){0.f, 0.f, 0.f, 0.f};
    float mrun[4], lrun[4];
    #pragma unroll
    for (int r = 0; r < 4; ++r) { mrun[r] = -__builtin_inff(); lrun[r] = 0.f; }

    const int srow = tid >> 3;        // 0..31
    const int scol = (tid & 7) * 8;   // 0..56

    for (int kt = 0; kt < 16; ++kt) {
        __syncthreads();
        // Stage K hi/lo [key][d] and Vt [d][key] tiles (vector copies).
        #pragma unroll
        for (int h = 0; h < 2; ++h) {
            const int r = srow + h * 32;
            const size_t gk = hb + (size_t)(kt * 64 + r) * DD + scol;
            *(bf16x8*)&KhiS[r * KST + scol] = *(const bf16x8*)(Khi + gk);
            *(bf16x8*)&KloS[r * KST + scol] = *(const bf16x8*)(Klo + gk);
            const size_t gv = hb + (size_t)r * NN + kt * 64 + scol;
            *(bf16x8*)&VtS[r * KST + scol]  = *(const bf16x8*)(Vt + gv);
        }
        __syncthreads();

        // S tile (16 q-rows x 64 keys per wave), 3-term split.
        f32x4 s[4];
        #pragma unroll
        for (int nt = 0; nt < 4; ++nt) s[nt] = (f32x4){0.f, 0.f, 0.f, 0.f};
        #pragma unroll
        for (int ks = 0; ks < 2; ++ks) {
            #pragma unroll
            for (int nt = 0; nt < 4; ++nt) {
                const int kidx = (nt * 16 + ln) * KST + ks * 32 + quad * 8;
                bf16x8 bh = *(const bf16x8*)&KhiS[kidx];
                bf16x8 bl = *(const bf16x8*)&KloS[kidx];
                s[nt] = __builtin_amdgcn_mfma_f32_16x16x32_bf16(qh[ks], bh, s[nt], 0, 0, 0);
                s[nt] = __builtin_amdgcn_mfma_f32_16x16x32_bf16(qh[ks], bl, s[nt], 0, 0, 0);
                s[nt] = __builtin_amdgcn_mfma_f32_16x16x32_bf16(ql[ks], bh, s[nt], 0, 0, 0);
            }
        }

        // Row max (rows = quad*4+r, spread over 16 lanes).
        float mx[4];
        #pragma unroll
        for (int r = 0; r < 4; ++r)
            mx[r] = fmaxf(fmaxf(s[0][r], s[1][r]), fmaxf(s[2][r], s[3][r]));
        #pragma unroll
        for (int msk = 1; msk <= 8; msk <<= 1) {
            #pragma unroll
            for (int r = 0; r < 4; ++r)
                mx[r] = fmaxf(mx[r], __shfl_xor(mx[r], msk, 64));
        }
        float alpha[4], rs[4];
        #pragma unroll
        for (int r = 0; r < 4; ++r) {
            const float mn = fmaxf(mrun[r], mx[r]);
            alpha[r] = __expf(mrun[r] - mn);   // 0 on first tile
            mrun[r] = mn;
            rs[r] = 0.f;
        }
        // P = exp(S-m): write bf16 into per-wave LDS (A-layout for PV).
        bf16_t* Pw = &PS[wave][0];
        #pragma unroll
        for (int nt = 0; nt < 4; ++nt) {
            #pragma unroll
            for (int r = 0; r < 4; ++r) {
                const float pe = __expf(s[nt][r] - mrun[r]);
                rs[r] += pe;
                Pw[(quad * 4 + r) * KST + nt * 16 + ln] = (bf16_t)pe;
            }
        }
        // Register-only work between P-store and barrier (hides fence cost).
        #pragma unroll
        for (int msk = 1; msk <= 8; msk <<= 1) {
            #pragma unroll
            for (int r = 0; r < 4; ++r)
                rs[r] += __shfl_xor(rs[r], msk, 64);
        }
        #pragma unroll
        for (int r = 0; r < 4; ++r) {
            lrun[r] = alpha[r] * lrun[r] + rs[r];
            o[0][r] *= alpha[r];
            o[1][r] *= alpha[r];
            o[2][r] *= alpha[r];
            o[3][r] *= alpha[r];
        }
        __syncthreads();   // RACE FIX: P-stores globally visible before ds_read_b128

        // O += P V  (P from per-wave LDS in A-layout; Vt B-frags).
        #pragma unroll
        for (int ks = 0; ks < 2; ++ks) {
            bf16x8 pa = *(const bf16x8*)&Pw[ln * KST + ks * 32 + quad * 8];
            #pragma unroll
            for (int dt = 0; dt < 4; ++dt) {
                bf16x8 vb = *(const bf16x8*)&VtS[(dt * 16 + ln) * KST + ks * 32 + quad * 8];
                o[dt] = __builtin_amdgcn_mfma_f32_16x16x32_bf16(pa, vb, o[dt], 0, 0, 0);
            }
        }
    }

    // Epilogue: out[b][p*64 + dt*16+ln][qt*64 + wave*16 + quad*4 + r]
    float inv[4];
    #pragma unroll
    for (int r = 0; r < 4; ++r) inv[r] = 1.0f / lrun[r];
    const int nbase = qt * 64 + wave * 16 + quad * 4;
    #pragma unroll
    for (int dt = 0; dt < 4; ++dt) {
        const int c = p * DD + dt * 16 + ln;
        float* op = out + ((size_t)b * CC + c) * NN + nbase;
        f32x4 ov;
        #pragma unroll
        for (int r = 0; r < 4; ++r) ov[r] = o[dt][r] * inv[r];
        *(f32x4*)op = ov;
    }
}

extern "C" void kernel_launch(void* const* d_in, const int* in_sizes, int n_in,
                              void* d_out, int out_size, void* d_ws, size_t ws_size,
                              hipStream_t stream) {
    const float* x     = (const float*)d_in[0];
    const float* qkv_w = (const float*)d_in[1];
    const float* h_pos = (const float*)d_in[2];
    const float* w_pos = (const float*)d_in[3];
    float* out = (float*)d_out;

    const size_t PT = (size_t)BB * HEADS * NN * DD;  // 16,777,216 elems
    bf16_t* Qhi = (bf16_t*)d_ws;
    bf16_t* Qlo = Qhi + PT;
    bf16_t* Khi = Qlo + PT;
    bf16_t* Klo = Khi + PT;
    bf16_t* Vt  = Klo + PT;   // total 5*PT*2 = 167.8 MB (fits: R2 mixed mode ran)

    qkv_kernel<<<dim3(24, 512), 256, 0, stream>>>(
        x, qkv_w, h_pos, w_pos, Qhi, Qlo, Khi, Klo, Vt);
    attn_kernel<<<dim3(16, HEADS, BB), 256, 0, stream>>>(
        Qhi, Qlo, Khi, Klo, Vt, out);
}

// Round 5
// 527.886 us; speedup vs baseline: 3.4161x; 2.0309x over previous
//
#include <hip/hip_runtime.h>
#include <hip/hip_bf16.h>
#include <hip/hip_fp16.h>

#define HEADS 8
#define BB 32
#define CC 512
#define NN 1024   // tokens
#define DD 64     // head dim

typedef _Float16 f16;
typedef __attribute__((ext_vector_type(8))) _Float16 f16x8;
typedef __attribute__((ext_vector_type(4))) _Float16 f16x4;
typedef __attribute__((ext_vector_type(4))) float f32x4;

// ---------------------------------------------------------------------------
// prep_x: xt[b][m][c] fp16  <-  x[b][c][m] fp32   (LDS 64x64 transpose)
// ---------------------------------------------------------------------------
__global__ __launch_bounds__(256) void prep_x(
    const float* __restrict__ x, f16* __restrict__ xt)
{
    __shared__ f16 T[64][65];
    const int tid = threadIdx.x;
    const int c0 = blockIdx.x * 64;   // 8 tiles
    const int m0 = blockIdx.y * 64;   // 16 tiles
    const int b  = blockIdx.z;
    const float* xb = x + (size_t)b * CC * NN;

    const int m_l = tid & 63, c_l = tid >> 6;
    #pragma unroll
    for (int s = 0; s < 16; ++s) {
        const int cr = s * 4 + c_l;
        T[cr][m_l] = (f16)xb[(size_t)(c0 + cr) * NN + m0 + m_l];
    }
    __syncthreads();
    const int m_r = tid >> 2, cq = (tid & 3) * 16;
    f16 buf[16];
    #pragma unroll
    for (int j = 0; j < 16; ++j) buf[j] = T[cq + j][m_r];
    f16* dst = xt + ((size_t)b * NN + m0 + m_r) * CC + c0 + cq;
    *(f16x8*)dst       = *(f16x8*)&buf[0];
    *(f16x8*)(dst + 8) = *(f16x8*)&buf[8];
}

// ---------------------------------------------------------------------------
// qkv_mfma: out[m][o] = sum_c xt[m][c] * W[o][c]   (fp16 MFMA, fp32 acc)
// A = xt (M=pixels), B = W (N=outputs).  Block tile 128m x 128o, BK=64.
// 4 waves: wave quadrant 64m x 64o.  W converted fp32->fp16 during staging.
// Epilogue: region 0 -> Qh [b][p][n][d]; region 1 -> Kh = K + rp;
//           region 2 -> Vt [b][p][d][n] (transposed, f16x4 packed stores).
// MFMA 16x16x32_f16: A[m=lane&15][k=quad*8+j], B[k=quad*8+j][n=lane&15],
// C/D row=quad*4+reg, col=lane&15.
// ---------------------------------------------------------------------------
#define QST 72

__global__ __launch_bounds__(256) void qkv_mfma(
    const f16*  __restrict__ xt,     // [B*N][C]
    const float* __restrict__ W,     // [3C][C]
    const float* __restrict__ h_pos, // [L][C]
    const float* __restrict__ w_pos, // [L][C]
    f16* __restrict__ Qh, f16* __restrict__ Kh, f16* __restrict__ Vt)
{
    __shared__ f16 Xs[128 * QST];
    __shared__ f16 Ws[128 * QST];

    const int tid  = threadIdx.x;
    const int wave = tid >> 6, lane = tid & 63;
    const int ln = lane & 15, quad = lane >> 4;
    const int o0  = blockIdx.x * 128;   // 12 tiles (fast dim -> share xt tile in L2)
    const int mg0 = blockIdx.y * 128;   // 256 tiles (global pixel index)
    const int mw = (wave & 1) * 64, ow = (wave >> 1) * 64;

    f32x4 acc[4][4];
    #pragma unroll
    for (int ia = 0; ia < 4; ++ia)
        #pragma unroll
        for (int ib = 0; ib < 4; ++ib) acc[ia][ib] = (f32x4){0.f, 0.f, 0.f, 0.f};

    const int srow = tid >> 1;          // 0..127
    const int ssub = (tid & 1) * 32;

    for (int ct = 0; ct < 8; ++ct) {
        const int c0 = ct * 64;
        __syncthreads();
        {
            const f16* xg = xt + (size_t)(mg0 + srow) * CC + c0 + ssub;
            #pragma unroll
            for (int i = 0; i < 4; ++i)
                *(f16x8*)&Xs[srow * QST + ssub + i * 8] = *(const f16x8*)(xg + i * 8);
            const float* wg = W + (size_t)(o0 + srow) * CC + c0 + ssub;
            #pragma unroll
            for (int i = 0; i < 8; ++i) {
                float4 wv = *(const float4*)(wg + i * 4);
                f16x4 wh = {(f16)wv.x, (f16)wv.y, (f16)wv.z, (f16)wv.w};
                *(f16x4*)&Ws[srow * QST + ssub + i * 4] = wh;
            }
        }
        __syncthreads();
        #pragma unroll
        for (int ks = 0; ks < 2; ++ks) {
            f16x8 a[4], bf[4];
            #pragma unroll
            for (int f = 0; f < 4; ++f) {
                a[f]  = *(const f16x8*)&Xs[(mw + f * 16 + ln) * QST + ks * 32 + quad * 8];
                bf[f] = *(const f16x8*)&Ws[(ow + f * 16 + ln) * QST + ks * 32 + quad * 8];
            }
            #pragma unroll
            for (int ia = 0; ia < 4; ++ia)
                #pragma unroll
                for (int ib = 0; ib < 4; ++ib)
                    acc[ia][ib] = __builtin_amdgcn_mfma_f32_16x16x32_f16(
                        a[ia], bf[ib], acc[ia][ib], 0, 0, 0);
        }
    }

    // Epilogue.  o-tile (128) lies within one region (512); wave's 64-wide
    // o-quadrant lies within one head.
    const int region = o0 >> 9;             // 0=Q, 1=K, 2=V
    const int ob = o0 + ow;                 // 64-aligned
    const int p  = (ob >> 6) & 7;
    const int b  = mg0 >> 10;
    const int n0 = (mg0 & 1023) + mw;       // + ia*16 + quad*4 + r

    if (region < 2) {
        f16* dst = (region == 0) ? Qh : Kh;
        const size_t hb = (size_t)(b * HEADS + p) * NN * DD;
        #pragma unroll
        for (int ib = 0; ib < 4; ++ib) {
            const int d = ib * 16 + ln;
            #pragma unroll
            for (int ia = 0; ia < 4; ++ia) {
                #pragma unroll
                for (int r = 0; r < 4; ++r) {
                    const int n = n0 + ia * 16 + quad * 4 + r;
                    float v = acc[ia][ib][r];
                    if (region == 1) {
                        const int c = p * DD + d;
                        v += h_pos[(n >> 5) * CC + c] + w_pos[(n & 31) * CC + c];
                    }
                    dst[hb + (size_t)n * DD + d] = (f16)v;
                }
            }
        }
    } else {
        const size_t vb = (size_t)(b * HEADS + p) * DD * NN;
        #pragma unroll
        for (int ib = 0; ib < 4; ++ib) {
            const int d = ib * 16 + ln;
            #pragma unroll
            for (int ia = 0; ia < 4; ++ia) {
                const int n = n0 + ia * 16 + quad * 4;
                f16x4 pk = {(f16)acc[ia][ib][0], (f16)acc[ia][ib][1],
                            (f16)acc[ia][ib][2], (f16)acc[ia][ib][3]};
                *(f16x4*)&Vt[vb + (size_t)d * NN + n] = pk;
            }
        }
    }
}

// ---------------------------------------------------------------------------
// attn_kernel: fp16 MFMA flash attention (single-term scores).
// Block = (qt, head, batch): 64 q-rows, 4 waves (16 q-rows each).
// Online softmax in registers; P -> per-wave LDS (C->A layout); PV via MFMA.
// __syncthreads() between P ds_write and PV ds_read (R4 race fix).
// ---------------------------------------------------------------------------
#define KST 72

__global__ __launch_bounds__(256) void attn_kernel(
    const f16* __restrict__ Qh, const f16* __restrict__ Kh,
    const f16* __restrict__ Vt, float* __restrict__ out)
{
    __shared__ f16 KS [64 * KST];
    __shared__ f16 VtS[64 * KST];
    __shared__ f16 PS [4][16 * KST];

    const int tid  = threadIdx.x;
    const int wave = tid >> 6;
    const int lane = tid & 63;
    const int ln   = lane & 15;
    const int quad = lane >> 4;

    const int qt = blockIdx.x;
    const int p  = blockIdx.y;
    const int b  = blockIdx.z;
    const size_t hb = (size_t)(b * HEADS + p) * NN * DD;

    // Q fragments (A-layout) straight from global, once.
    const int qrow = qt * 64 + wave * 16 + ln;
    f16x8 qf[2];
    #pragma unroll
    for (int ks = 0; ks < 2; ++ks)
        qf[ks] = *(const f16x8*)(Qh + hb + (size_t)qrow * DD + ks * 32 + quad * 8);

    f32x4 o[4];
    #pragma unroll
    for (int dt = 0; dt < 4; ++dt) o[dt] = (f32x4){0.f, 0.f, 0.f, 0.f};
    float mrun[4], lrun[4];
    #pragma unroll
    for (int r = 0; r < 4; ++r) { mrun[r] = -__builtin_inff(); lrun[r] = 0.f; }

    const int sr = tid >> 2, sc = (tid & 3) * 16;   // staging map: 64 rows x 64 cols

    for (int kt = 0; kt < 16; ++kt) {
        __syncthreads();
        // Stage K [key][d] and Vt [d][key] tiles (pure f16x8 copies).
        {
            const size_t gk = hb + (size_t)(kt * 64 + sr) * DD + sc;
            *(f16x8*)&KS[sr * KST + sc]     = *(const f16x8*)(Kh + gk);
            *(f16x8*)&KS[sr * KST + sc + 8] = *(const f16x8*)(Kh + gk + 8);
            const size_t gv = hb + (size_t)sr * NN + kt * 64 + sc;
            *(f16x8*)&VtS[sr * KST + sc]     = *(const f16x8*)(Vt + gv);
            *(f16x8*)&VtS[sr * KST + sc + 8] = *(const f16x8*)(Vt + gv + 8);
        }
        __syncthreads();

        // S tile (16 q-rows x 64 keys per wave).
        f32x4 s[4];
        #pragma unroll
        for (int nt = 0; nt < 4; ++nt) s[nt] = (f32x4){0.f, 0.f, 0.f, 0.f};
        #pragma unroll
        for (int ks = 0; ks < 2; ++ks) {
            #pragma unroll
            for (int nt = 0; nt < 4; ++nt) {
                f16x8 bk = *(const f16x8*)&KS[(nt * 16 + ln) * KST + ks * 32 + quad * 8];
                s[nt] = __builtin_amdgcn_mfma_f32_16x16x32_f16(qf[ks], bk, s[nt], 0, 0, 0);
            }
        }

        // Row max (rows = quad*4+r, spread over 16 lanes).
        float mx[4];
        #pragma unroll
        for (int r = 0; r < 4; ++r)
            mx[r] = fmaxf(fmaxf(s[0][r], s[1][r]), fmaxf(s[2][r], s[3][r]));
        #pragma unroll
        for (int msk = 1; msk <= 8; msk <<= 1) {
            #pragma unroll
            for (int r = 0; r < 4; ++r)
                mx[r] = fmaxf(mx[r], __shfl_xor(mx[r], msk, 64));
        }
        float alpha[4], rs[4];
        #pragma unroll
        for (int r = 0; r < 4; ++r) {
            const float mn = fmaxf(mrun[r], mx[r]);
            alpha[r] = __expf(mrun[r] - mn);   // 0 on first tile
            mrun[r] = mn;
            rs[r] = 0.f;
        }
        // P = exp(S-m) -> fp16 into per-wave LDS (A-layout rows for PV).
        f16* Pw = &PS[wave][0];
        #pragma unroll
        for (int nt = 0; nt < 4; ++nt) {
            #pragma unroll
            for (int r = 0; r < 4; ++r) {
                const float pe = __expf(s[nt][r] - mrun[r]);
                rs[r] += pe;
                Pw[(quad * 4 + r) * KST + nt * 16 + ln] = (f16)pe;
            }
        }
        // Register-only work between P-store and barrier.
        #pragma unroll
        for (int msk = 1; msk <= 8; msk <<= 1) {
            #pragma unroll
            for (int r = 0; r < 4; ++r)
                rs[r] += __shfl_xor(rs[r], msk, 64);
        }
        #pragma unroll
        for (int r = 0; r < 4; ++r) {
            lrun[r] = alpha[r] * lrun[r] + rs[r];
            o[0][r] *= alpha[r];
            o[1][r] *= alpha[r];
            o[2][r] *= alpha[r];
            o[3][r] *= alpha[r];
        }
        __syncthreads();   // P-stores visible before ds_read_b128 (race fix)

        // O += P V.
        #pragma unroll
        for (int ks = 0; ks < 2; ++ks) {
            f16x8 pa = *(const f16x8*)&Pw[ln * KST + ks * 32 + quad * 8];
            #pragma unroll
            for (int dt = 0; dt < 4; ++dt) {
                f16x8 vb = *(const f16x8*)&VtS[(dt * 16 + ln) * KST + ks * 32 + quad * 8];
                o[dt] = __builtin_amdgcn_mfma_f32_16x16x32_f16(pa, vb, o[dt], 0, 0, 0);
            }
        }
    }

    // Epilogue: out[b][p*64 + dt*16+ln][qt*64 + wave*16 + quad*4 + r]
    float inv[4];
    #pragma unroll
    for (int r = 0; r < 4; ++r) inv[r] = 1.0f / lrun[r];
    const int nbase = qt * 64 + wave * 16 + quad * 4;
    #pragma unroll
    for (int dt = 0; dt < 4; ++dt) {
        const int c = p * DD + dt * 16 + ln;
        float* op = out + ((size_t)b * CC + c) * NN + nbase;
        f32x4 ov;
        #pragma unroll
        for (int r = 0; r < 4; ++r) ov[r] = o[dt][r] * inv[r];
        *(f32x4*)op = ov;
    }
}

extern "C" void kernel_launch(void* const* d_in, const int* in_sizes, int n_in,
                              void* d_out, int out_size, void* d_ws, size_t ws_size,
                              hipStream_t stream) {
    const float* x     = (const float*)d_in[0];
    const float* qkv_w = (const float*)d_in[1];
    const float* h_pos = (const float*)d_in[2];
    const float* w_pos = (const float*)d_in[3];
    float* out = (float*)d_out;

    const size_t PT = (size_t)BB * HEADS * NN * DD;  // 16,777,216 elems
    f16* xt = (f16*)d_ws;
    f16* Qh = xt + PT;
    f16* Kh = Qh + PT;
    f16* Vt = Kh + PT;   // total 4*PT*2 = 134.2 MB (under the 167.8 MB that fit)

    prep_x<<<dim3(CC / 64, NN / 64, BB), 256, 0, stream>>>(x, xt);
    qkv_mfma<<<dim3(12, 256), 256, 0, stream>>>(xt, qkv_w, h_pos, w_pos, Qh, Kh, Vt);
    attn_kernel<<<dim3(16, HEADS, BB), 256, 0, stream>>>(Qh, Kh, Vt, out);
}

// Round 7
// 430.566 us; speedup vs baseline: 4.1882x; 1.2260x over previous
//
#include <hip/hip_runtime.h>
#include <hip/hip_bf16.h>
#include <hip/hip_fp16.h>

#define HEADS 8
#define BB 32
#define CC 512
#define NN 1024   // tokens
#define DD 64     // head dim

typedef _Float16 f16;
typedef __attribute__((ext_vector_type(8))) _Float16 f16x8;
typedef __attribute__((ext_vector_type(4))) _Float16 f16x4;
typedef __attribute__((ext_vector_type(4))) float f32x4;

// ---------------------------------------------------------------------------
// wconv: W fp32 [3C][C] -> Wh fp16 (one-time, ~1.5 MB)
// ---------------------------------------------------------------------------
__global__ __launch_bounds__(256) void wconv(
    const float* __restrict__ W, f16* __restrict__ Wh)
{
    const size_t i = ((size_t)blockIdx.x * 256 + threadIdx.x) * 8;
    float4 a = *(const float4*)(W + i);
    float4 b = *(const float4*)(W + i + 4);
    f16x8 h = {(f16)a.x, (f16)a.y, (f16)a.z, (f16)a.w,
               (f16)b.x, (f16)b.y, (f16)b.z, (f16)b.w};
    *(f16x8*)(Wh + i) = h;
}

// ---------------------------------------------------------------------------
// prep_x: xt[b][m][c] fp16  <-  x[b][c][m] fp32   (LDS 64x64 transpose)
// ---------------------------------------------------------------------------
__global__ __launch_bounds__(256) void prep_x(
    const float* __restrict__ x, f16* __restrict__ xt)
{
    __shared__ f16 T[64][65];
    const int tid = threadIdx.x;
    const int c0 = blockIdx.x * 64;
    const int m0 = blockIdx.y * 64;
    const int b  = blockIdx.z;
    const float* xb = x + (size_t)b * CC * NN;

    const int m_l = tid & 63, c_l = tid >> 6;
    #pragma unroll
    for (int s = 0; s < 16; ++s) {
        const int cr = s * 4 + c_l;
        T[cr][m_l] = (f16)xb[(size_t)(c0 + cr) * NN + m0 + m_l];
    }
    __syncthreads();
    const int m_r = tid >> 2, cq = (tid & 3) * 16;
    f16 buf[16];
    #pragma unroll
    for (int j = 0; j < 16; ++j) buf[j] = T[cq + j][m_r];
    f16* dst = xt + ((size_t)b * NN + m0 + m_r) * CC + c0 + cq;
    *(f16x8*)dst       = *(f16x8*)&buf[0];
    *(f16x8*)(dst + 8) = *(f16x8*)&buf[8];
}

// ---------------------------------------------------------------------------
// qkv_mfma: out[m][o] = sum_c xt[m][c] * Wh[o][c]   (fp16 MFMA, fp32 acc)
// Block tile 128m x 128o, BK=64; 4 waves, each 64m x 64o.  Pure f16x8 staging.
// Epilogue: Qh [b][p][n][d]; Kh = K + rp; Vt [b][p][d][n] (transposed).
// MFMA 16x16x32_f16: A[m=lane&15][k=quad*8+j], B[k=quad*8+j][n=lane&15],
// C/D row=quad*4+reg, col=lane&15.
// ---------------------------------------------------------------------------
#define QST 72

__global__ __launch_bounds__(256) void qkv_mfma(
    const f16*  __restrict__ xt,     // [B*N][C]
    const f16*  __restrict__ Wh,     // [3C][C]
    const float* __restrict__ h_pos, // [L][C]
    const float* __restrict__ w_pos, // [L][C]
    f16* __restrict__ Qh, f16* __restrict__ Kh, f16* __restrict__ Vt)
{
    __shared__ f16 Xs[128 * QST];
    __shared__ f16 Ws[128 * QST];

    const int tid  = threadIdx.x;
    const int wave = tid >> 6, lane = tid & 63;
    const int ln = lane & 15, quad = lane >> 4;
    const int o0  = blockIdx.x * 128;
    const int mg0 = blockIdx.y * 128;
    const int mw = (wave & 1) * 64, ow = (wave >> 1) * 64;

    f32x4 acc[4][4];
    #pragma unroll
    for (int ia = 0; ia < 4; ++ia)
        #pragma unroll
        for (int ib = 0; ib < 4; ++ib) acc[ia][ib] = (f32x4){0.f, 0.f, 0.f, 0.f};

    const int srow = tid >> 1;
    const int ssub = (tid & 1) * 32;

    for (int ct = 0; ct < 8; ++ct) {
        const int c0 = ct * 64;
        __syncthreads();
        {
            const f16* xg = xt + (size_t)(mg0 + srow) * CC + c0 + ssub;
            const f16* wg = Wh + (size_t)(o0 + srow) * CC + c0 + ssub;
            #pragma unroll
            for (int i = 0; i < 4; ++i) {
                *(f16x8*)&Xs[srow * QST + ssub + i * 8] = *(const f16x8*)(xg + i * 8);
                *(f16x8*)&Ws[srow * QST + ssub + i * 8] = *(const f16x8*)(wg + i * 8);
            }
        }
        __syncthreads();
        #pragma unroll
        for (int ks = 0; ks < 2; ++ks) {
            f16x8 a[4], bf[4];
            #pragma unroll
            for (int f = 0; f < 4; ++f) {
                a[f]  = *(const f16x8*)&Xs[(mw + f * 16 + ln) * QST + ks * 32 + quad * 8];
                bf[f] = *(const f16x8*)&Ws[(ow + f * 16 + ln) * QST + ks * 32 + quad * 8];
            }
            #pragma unroll
            for (int ia = 0; ia < 4; ++ia)
                #pragma unroll
                for (int ib = 0; ib < 4; ++ib)
                    acc[ia][ib] = __builtin_amdgcn_mfma_f32_16x16x32_f16(
                        a[ia], bf[ib], acc[ia][ib], 0, 0, 0);
        }
    }

    const int region = o0 >> 9;             // 0=Q, 1=K, 2=V
    const int ob = o0 + ow;
    const int p  = (ob >> 6) & 7;
    const int b  = mg0 >> 10;
    const int n0 = (mg0 & 1023) + mw;

    if (region < 2) {
        f16* dst = (region == 0) ? Qh : Kh;
        const size_t hb = (size_t)(b * HEADS + p) * NN * DD;
        #pragma unroll
        for (int ib = 0; ib < 4; ++ib) {
            const int d = ib * 16 + ln;
            #pragma unroll
            for (int ia = 0; ia < 4; ++ia) {
                #pragma unroll
                for (int r = 0; r < 4; ++r) {
                    const int n = n0 + ia * 16 + quad * 4 + r;
                    float v = acc[ia][ib][r];
                    if (region == 1) {
                        const int c = p * DD + d;
                        v += h_pos[(n >> 5) * CC + c] + w_pos[(n & 31) * CC + c];
                    }
                    dst[hb + (size_t)n * DD + d] = (f16)v;
                }
            }
        }
    } else {
        const size_t vb = (size_t)(b * HEADS + p) * DD * NN;
        #pragma unroll
        for (int ib = 0; ib < 4; ++ib) {
            const int d = ib * 16 + ln;
            #pragma unroll
            for (int ia = 0; ia < 4; ++ia) {
                const int n = n0 + ia * 16 + quad * 4;
                f16x4 pk = {(f16)acc[ia][ib][0], (f16)acc[ia][ib][1],
                            (f16)acc[ia][ib][2], (f16)acc[ia][ib][3]};
                *(f16x4*)&Vt[vb + (size_t)d * NN + n] = pk;
            }
        }
    }
}

// ---------------------------------------------------------------------------
// attn_kernel: fp16 MFMA flash attention.
// R7 bisect: row-max back to __shfl_xor (R4/R5-proven ds_swizzle path;
// R6's DPP-after-MFMA reduction is the prime replay-divergence suspect).
// Row-sum stays on the MFMA pipe: l_acc = mfma(P, ones, alpha*l_acc).
// Layouts identical to verified R5.  B3 race-fix barrier retained.
// ---------------------------------------------------------------------------
#define KST 72

__global__ __launch_bounds__(256) void attn_kernel(
    const f16* __restrict__ Qh, const f16* __restrict__ Kh,
    const f16* __restrict__ Vt, float* __restrict__ out)
{
    __shared__ f16 KS [64 * KST];
    __shared__ f16 VtS[64 * KST];
    __shared__ f16 PS [4][16 * KST];

    const int tid  = threadIdx.x;
    const int wave = tid >> 6;
    const int lane = tid & 63;
    const int ln   = lane & 15;
    const int quad = lane >> 4;

    const int qt = blockIdx.x;
    const int p  = blockIdx.y;
    const int b  = blockIdx.z;
    const size_t hb = (size_t)(b * HEADS + p) * NN * DD;

    const int qrow = qt * 64 + wave * 16 + ln;
    f16x8 qf[2];
    #pragma unroll
    for (int ks = 0; ks < 2; ++ks)
        qf[ks] = *(const f16x8*)(Qh + hb + (size_t)qrow * DD + ks * 32 + quad * 8);

    const f16x8 ones = {(f16)1.f, (f16)1.f, (f16)1.f, (f16)1.f,
                        (f16)1.f, (f16)1.f, (f16)1.f, (f16)1.f};

    f32x4 o[4];
    #pragma unroll
    for (int dt = 0; dt < 4; ++dt) o[dt] = (f32x4){0.f, 0.f, 0.f, 0.f};
    f32x4 lacc = (f32x4){0.f, 0.f, 0.f, 0.f};
    float mrun[4];
    #pragma unroll
    for (int r = 0; r < 4; ++r) mrun[r] = -__builtin_inff();

    const int sr = tid >> 2, sc = (tid & 3) * 16;

    for (int kt = 0; kt < 16; ++kt) {
        __syncthreads();   // B1
        // Stage K [key][d] and Vt [d][key] tiles (pure f16x8 copies).
        {
            const size_t gk = hb + (size_t)(kt * 64 + sr) * DD + sc;
            *(f16x8*)&KS[sr * KST + sc]     = *(const f16x8*)(Kh + gk);
            *(f16x8*)&KS[sr * KST + sc + 8] = *(const f16x8*)(Kh + gk + 8);
            const size_t gv = hb + (size_t)sr * NN + kt * 64 + sc;
            *(f16x8*)&VtS[sr * KST + sc]     = *(const f16x8*)(Vt + gv);
            *(f16x8*)&VtS[sr * KST + sc + 8] = *(const f16x8*)(Vt + gv + 8);
        }
        __syncthreads();   // B2

        // S tile (16 q-rows x 64 keys per wave).
        f32x4 s[4];
        #pragma unroll
        for (int nt = 0; nt < 4; ++nt) s[nt] = (f32x4){0.f, 0.f, 0.f, 0.f};
        #pragma unroll
        for (int ks = 0; ks < 2; ++ks) {
            #pragma unroll
            for (int nt = 0; nt < 4; ++nt) {
                f16x8 bk = *(const f16x8*)&KS[(nt * 16 + ln) * KST + ks * 32 + quad * 8];
                s[nt] = __builtin_amdgcn_mfma_f32_16x16x32_f16(qf[ks], bk, s[nt], 0, 0, 0);
            }
        }

        // Row max via __shfl_xor (rows = quad*4+r, spread over 16 lanes).
        float mx[4];
        #pragma unroll
        for (int r = 0; r < 4; ++r)
            mx[r] = fmaxf(fmaxf(s[0][r], s[1][r]), fmaxf(s[2][r], s[3][r]));
        #pragma unroll
        for (int msk = 1; msk <= 8; msk <<= 1) {
            #pragma unroll
            for (int r = 0; r < 4; ++r)
                mx[r] = fmaxf(mx[r], __shfl_xor(mx[r], msk, 64));
        }
        float alpha[4];
        #pragma unroll
        for (int r = 0; r < 4; ++r) {
            const float mn = fmaxf(mrun[r], mx[r]);
            alpha[r] = __expf(mrun[r] - mn);   // 0 on first tile
            mrun[r] = mn;
        }
        // P = exp(S-m) -> fp16 into per-wave LDS (A-layout rows for PV).
        f16* Pw = &PS[wave][0];
        #pragma unroll
        for (int nt = 0; nt < 4; ++nt) {
            #pragma unroll
            for (int r = 0; r < 4; ++r) {
                const float pe = __expf(s[nt][r] - mrun[r]);
                Pw[(quad * 4 + r) * KST + nt * 16 + ln] = (f16)pe;
            }
        }
        // Register-only rescale between P-store and barrier.
        #pragma unroll
        for (int r = 0; r < 4; ++r) {
            lacc[r] *= alpha[r];
            o[0][r] *= alpha[r];
            o[1][r] *= alpha[r];
            o[2][r] *= alpha[r];
            o[3][r] *= alpha[r];
        }
        __syncthreads();   // B3: P-stores visible before ds_read_b128

        // O += P V ; l += P 1  (sum on the MFMA pipe, reusing pa frags).
        #pragma unroll
        for (int ks = 0; ks < 2; ++ks) {
            f16x8 pa = *(const f16x8*)&Pw[ln * KST + ks * 32 + quad * 8];
            lacc = __builtin_amdgcn_mfma_f32_16x16x32_f16(pa, ones, lacc, 0, 0, 0);
            #pragma unroll
            for (int dt = 0; dt < 4; ++dt) {
                f16x8 vb = *(const f16x8*)&VtS[(dt * 16 + ln) * KST + ks * 32 + quad * 8];
                o[dt] = __builtin_amdgcn_mfma_f32_16x16x32_f16(pa, vb, o[dt], 0, 0, 0);
            }
        }
    }

    // Epilogue: out[b][p*64 + dt*16+ln][qt*64 + wave*16 + quad*4 + r]
    float inv[4];
    #pragma unroll
    for (int r = 0; r < 4; ++r) inv[r] = 1.0f / lacc[r];
    const int nbase = qt * 64 + wave * 16 + quad * 4;
    #pragma unroll
    for (int dt = 0; dt < 4; ++dt) {
        const int c = p * DD + dt * 16 + ln;
        float* op = out + ((size_t)b * CC + c) * NN + nbase;
        f32x4 ov;
        #pragma unroll
        for (int r = 0; r < 4; ++r) ov[r] = o[dt][r] * inv[r];
        *(f32x4*)op = ov;
    }
}

extern "C" void kernel_launch(void* const* d_in, const int* in_sizes, int n_in,
                              void* d_out, int out_size, void* d_ws, size_t ws_size,
                              hipStream_t stream) {
    const float* x     = (const float*)d_in[0];
    const float* qkv_w = (const float*)d_in[1];
    const float* h_pos = (const float*)d_in[2];
    const float* w_pos = (const float*)d_in[3];
    float* out = (float*)d_out;

    const size_t PT = (size_t)BB * HEADS * NN * DD;  // 16,777,216 elems
    f16* xt = (f16*)d_ws;
    f16* Qh = xt + PT;
    f16* Kh = Qh + PT;
    f16* Vt = Kh + PT;
    f16* Wh = Vt + PT;   // 3C*C = 786,432 f16; total ~135.7 MB (fits)

    wconv<<<dim3(3 * CC * CC / (256 * 8)), 256, 0, stream>>>(qkv_w, Wh);
    prep_x<<<dim3(CC / 64, NN / 64, BB), 256, 0, stream>>>(x, xt);
    qkv_mfma<<<dim3(12, 256), 256, 0, stream>>>(xt, Wh, h_pos, w_pos, Qh, Kh, Vt);
    attn_kernel<<<dim3(16, HEADS, BB), 256, 0, stream>>>(Qh, Kh, Vt, out);
}